// Round 1
// baseline (90.358 us; speedup 1.0000x reference)
//
#include <hip/hip_runtime.h>

#define SEQ 8192
#define DIM 128
#define QR  4                          // query rows per wave
#define WPB 8                          // waves per block
#define RPB (QR * WPB)                 // 32 rows per block
#define NB  (2 * SEQ / RPB)            // 512 blocks = exactly 2/CU
#define SROWS (RPB + 60)               // 92 staged K/V rows: [blk-60, blk+31]
#define NSLOT (SROWS * 32)             // 2944 float4 slots

// fp32 in / fp32 out. One wave handles QR=4 consecutive query rows [r0,r0+3];
// lane l owns key j = r0-60+l. Row rr's window is [r0-60, r0+rr] (61..64
// keys); dropped keys carry bias <= -61 -> relative weight < e^-50, invisible
// at fp32. Global sinks (j<100) only matter for rows i<164, where the window
// covers them.
//
// R7 changes vs R6 (~45us kernel):
//  * q staged in LDS (broadcast ds_read_b128) -- kills the in-loop scalar
//    q loads that serialized QK on scalar-cache miss latency.
//  * V staged into the SAME LDS buffer as K after QK completes (K is dead
//    post-scores) -- kills the 64 per-row global loads in PV that thrashed
//    the 32KB L1 (CU-level V working set ~160KB). Same XOR swizzle; the
//    vr<0 clamp moves to staging (masked lanes have weight exactly 0).
//  * Block doubled to 32 rows / 8 waves: staged-window redundancy 92/32 vs
//    76/16 rows, LDS 63,488B -> exactly 2 blocks/CU, 16 waves/CU, one clean
//    residency round (512 blocks on 256 CUs).
__global__ __launch_bounds__(512) void lminf_kernel(
    const float* __restrict__ qg,
    const float* __restrict__ kg,
    const float* __restrict__ vg,
    float* __restrict__ og)
{
    const int tid  = threadIdx.x;
    const int lane = tid & 63;
    const int wv   = __builtin_amdgcn_readfirstlane(tid >> 6); // uniform
    const int blkrow0 = (blockIdx.x * RPB) & (SEQ - 1);        // block's first row
    const int r0   = blkrow0 + wv * QR;                        // wave's first row
    const long base = (long)((blockIdx.x * RPB) >> 13) * (SEQ * DIM);

    __shared__ float4 kvds[NSLOT];      // 47,104 B: K rows, then reused for V
    __shared__ float4 qds[RPB * 32];    // 16,384 B: block's 32 q rows

    // ---- stage K rows [blkrow0-60, blkrow0+31] coalesced, XOR-swizzled ----
    {
        const float4* kgp = (const float4*)(kg + base);
        #pragma unroll
        for (int it = 0; it < 6; ++it) {                // 6*512 >= 2944
            const int g = it * 512 + tid;
            if (g < NSLOT) {
                const int row = g >> 5;
                const int c   = g & 31;
                int gr = blkrow0 - 60 + row;
                if (gr < 0) gr = 0;                     // clamped rows never used
                kvds[row * 32 + (c ^ (row & 7))] = kgp[gr * 32 + c];
            }
        }
        // q rows are contiguous: qds[g] = q[blkrow0*32 + g]
        const float4* qgp = (const float4*)(qg + base) + blkrow0 * 32;
        #pragma unroll
        for (int it = 0; it < 2; ++it) {                // 2*512 = 1024 slots
            const int g = it * 512 + tid;
            qds[g] = qgp[g];
        }
    }
    __syncthreads();

    // ---- QK: lane's K row from LDS (conflict-free b128); q via LDS broadcast ----
    const int w0 = r0 - 60;                     // key owned by lane 0
    const int j  = w0 + lane;
    const int lr = wv * QR + lane;              // staged local row of key j (<=91)
    const int sw = lr & 7;
    const float4* krow = &kvds[lr * 32];
    const float4* qrow = &qds[(wv * QR) * 32];  // wave's 4 q rows, uniform addr

    float acc[QR] = {0.f, 0.f, 0.f, 0.f};
    #pragma unroll 8
    for (int c = 0; c < 32; ++c) {
        const float4 kk = krow[c ^ sw];
        #pragma unroll
        for (int rr = 0; rr < QR; ++rr) {
            const float4 qq = qrow[rr * 32 + c];        // broadcast ds_read_b128
            acc[rr] += qq.x * kk.x + qq.y * kk.y + qq.z * kk.z + qq.w * kk.w;
        }
    }

    // ---- softmax per row across 64 lanes (mask -3e38, expf underflow) ----
    float w[QR];
    #pragma unroll
    for (int rr = 0; rr < QR; ++rr) {
        const int i = r0 + rr;
        float s = acc[rr] * 0.08838834764831845f + (float)(j - i);  // bias
        if (j > i || j < 0) s = -3.0e38f;    // causal + left-edge mask
        float m = s;
        #pragma unroll
        for (int off = 32; off; off >>= 1) m = fmaxf(m, __shfl_xor(m, off));
        const float e = __expf(s - m);       // masked lanes -> exact 0
        float l = e;
        #pragma unroll
        for (int off = 32; off; off >>= 1) l += __shfl_xor(l, off);
        w[rr] = e * (1.0f / l);              // l >= 1 (max lane gives 1)
    }

    // ---- all QK reads of kvds done -> restage V into the same buffer ----
    __syncthreads();
    {
        const float4* vgp = (const float4*)(vg + base);
        #pragma unroll
        for (int it = 0; it < 6; ++it) {
            const int g = it * 512 + tid;
            if (g < NSLOT) {
                const int row = g >> 5;
                const int c   = g & 31;
                int gr = blkrow0 - 60 + row;
                if (gr < 0) gr = 0;                 // weight 0 -> garbage*0 = 0
                kvds[row * 32 + (c ^ (row & 7))] = vgp[gr * 32 + c];
            }
        }
    }
    __syncthreads();

    // ---- PV: lane owns dims {2*lane, 2*lane+1}; V from LDS (uniform row,
    //      conflict-free); weights via v_readlane ----
    float o0[QR] = {0.f, 0.f, 0.f, 0.f};
    float o1[QR] = {0.f, 0.f, 0.f, 0.f};
    const char* vb = (const char*)kvds;
    #pragma unroll 8
    for (int k = 0; k < 64; ++k) {
        const int vr = wv * QR + k;          // uniform staged V row (<=91)
        const int cc = (lane >> 1) ^ (vr & 7);
        const float2 vpair =
            *(const float2*)(vb + vr * 512 + cc * 16 + (lane & 1) * 8);
        const float wk0 = __int_as_float(
            __builtin_amdgcn_readlane(__float_as_int(w[0]), k));
        const float wk1 = __int_as_float(
            __builtin_amdgcn_readlane(__float_as_int(w[1]), k));
        const float wk2 = __int_as_float(
            __builtin_amdgcn_readlane(__float_as_int(w[2]), k));
        const float wk3 = __int_as_float(
            __builtin_amdgcn_readlane(__float_as_int(w[3]), k));
        o0[0] += wk0 * vpair.x;  o1[0] += wk0 * vpair.y;
        o0[1] += wk1 * vpair.x;  o1[1] += wk1 * vpair.y;
        o0[2] += wk2 * vpair.x;  o1[2] += wk2 * vpair.y;
        o0[3] += wk3 * vpair.x;  o1[3] += wk3 * vpair.y;
    }

    // ---- store fp32 float2 per lane per row (coalesced) ----
    #pragma unroll
    for (int rr = 0; rr < QR; ++rr) {
        ((float2*)(og + base + (long)(r0 + rr) * DIM))[lane] =
            make_float2(o0[rr], o1[rr]);
    }
}

extern "C" void kernel_launch(void* const* d_in, const int* in_sizes, int n_in,
                              void* d_out, int out_size, void* d_ws, size_t ws_size,
                              hipStream_t stream) {
    const float* q = (const float*)d_in[0];
    const float* k = (const float*)d_in[1];
    const float* v = (const float*)d_in[2];
    float* out = (float*)d_out;

    lminf_kernel<<<NB, 512, 0, stream>>>(q, k, v, out);
}